// Round 4
// baseline (529.866 us; speedup 1.0000x reference)
//
#include <hip/hip_runtime.h>
#include <hip/hip_bf16.h>
#include <math.h>

// Problem constants (B=2, S=1024, E=1024, H=16, D=64)
#define S_LEN 1024
#define E_DIM 1024
#define NH 16
#define HD 64
#define M_ROWS 2048   // B*S
#define BH_CNT 32     // B*NH

static constexpr float LR_C = 0.01f;
static constexpr float SC_C = 0.125f;                // 1/sqrt(64)
static constexpr float C2_C = 0.125f * 1.44269504f;  // SC * log2(e): log2-domain softmax

typedef unsigned short ushort_t;
typedef __attribute__((ext_vector_type(8))) __bf16 bf16x8;
typedef __attribute__((ext_vector_type(4))) float f32x4;

static __device__ inline ushort_t f2bu(float f) {
  __hip_bfloat16 h = __float2bfloat16(f);
  return *(ushort_t*)&h;
}
static __device__ inline bf16x8 ldg8(const ushort_t* p) { return *(const bf16x8*)p; }

// XOR-swizzled index into an unpadded 64x64 ushort LDS tile.
// Row stride 64 (128B). Swizzle rotates 16B slots within the row by (row&7):
// b128 reads at stride-64 rows spread across banks exactly as well as the old
// +8 padding (uniform 8x = LDS b128 throughput floor), at 8KB instead of 9.2KB.
static __device__ inline int swz(int r, int c) { return (r * 64 + c) ^ ((r & 7) << 3); }

// async global->LDS, 16B per lane; LDS dest = wave-uniform base + lane*16
static __device__ inline void async_cp16(const ushort_t* g, __bf16* lds_wave_base) {
  __builtin_amdgcn_global_load_lds((const __attribute__((address_space(1))) void*)g,
                                   (__attribute__((address_space(3))) void*)lds_wave_base,
                                   16, 0, 0);
}

// ---------------- weight prep: bf16 cast + bf16 transpose, 64x64 tiles ----------------
__global__ __launch_bounds__(256) void prep_w(const float* __restrict__ W,
                                              ushort_t* __restrict__ Wb,
                                              ushort_t* __restrict__ WTb) {
  __shared__ float ts[64][65];
  int bx = blockIdx.x * 64, by = blockIdx.y * 64;
  int t = threadIdx.x;
  int rr = t >> 6, cc = t & 63;
  #pragma unroll
  for (int p = 0; p < 16; p++) {
    int r = p * 4 + rr;
    float v = W[(size_t)(by + r) * E_DIM + bx + cc];
    ts[r][cc] = v;
    Wb[(size_t)(by + r) * E_DIM + bx + cc] = f2bu(v);
  }
  __syncthreads();
  #pragma unroll
  for (int p = 0; p < 16; p++) {
    int r = p * 4 + rr;
    WTb[(size_t)(bx + r) * E_DIM + by + cc] = f2bu(ts[cc][r]);
  }
}

// ---------------- fp32 -> bf16 cast (float4-wide) ----------------
__global__ __launch_bounds__(256) void k_cast(const float* __restrict__ in,
                                              ushort_t* __restrict__ out, int n4) {
  int i = blockIdx.x * 256 + threadIdx.x;
  if (i < n4) {
    float4 v = ((const float4*)in)[i];
    ushort_t p[4] = {f2bu(v.x), f2bu(v.y), f2bu(v.z), f2bu(v.w)};
    *(uint2*)(out + (size_t)i * 4) = *(uint2*)p;
  }
}

// ---------------- N = 3LR*I - 3LR^2*M + LR^3*M2  (bf16 out) ----------------
__global__ __launch_bounds__(256) void k_formN(const float* __restrict__ Mf,
                                               const float* __restrict__ M2f,
                                               ushort_t* __restrict__ Nb) {
  int idx = blockIdx.x * 256 + threadIdx.x;   // 1M elements
  int i = idx >> 10, j = idx & 1023;
  float v = -3.f * LR_C * LR_C * Mf[idx] + LR_C * LR_C * LR_C * M2f[idx];
  if (i == j) v += 3.f * LR_C;
  Nb[idx] = f2bu(v);
}

// ---------------- iter-1 shortcut: suffix scan S[j] = sum_{i>=j} Xs[i]/(i+1) ----------------
// x=0 => Q=K=V=0 => P is exactly causal-uniform, dQ=dK=0, dV = P0^T(-Xs).
// x1 = LR * (P0^T Xs) * Wv. Two-pass chunked scan over the sequence dim.
__global__ __launch_bounds__(256) void k_scan1(const float* __restrict__ Xs,
                                               float* __restrict__ Sf,
                                               float* __restrict__ tot) {
  int e = blockIdx.x * 256 + threadIdx.x;  // column 0..1023
  int b = blockIdx.y;                      // batch
  int z = blockIdx.z;                      // chunk 0..15 (64 rows each)
  float acc = 0.f;
  for (int i = z * 64 + 63; i >= z * 64; i--) {
    size_t idx = ((size_t)b * S_LEN + i) * E_DIM + e;
    acc = fmaf(Xs[idx], 1.0f / (float)(i + 1), acc);
    Sf[idx] = acc;
  }
  tot[((size_t)b * 16 + z) * E_DIM + e] = acc;
}

__global__ __launch_bounds__(256) void k_scan2(const float* __restrict__ Sf,
                                               const float* __restrict__ tot,
                                               ushort_t* __restrict__ Sb) {
  int e = blockIdx.x * 256 + threadIdx.x;
  int b = blockIdx.y;
  int z = blockIdx.z;
  float off = 0.f;
  for (int c = z + 1; c < 16; c++) off += tot[((size_t)b * 16 + c) * E_DIM + e];
  for (int i = z * 64; i < z * 64 + 64; i++) {
    size_t idx = ((size_t)b * S_LEN + i) * E_DIM + e;
    Sb[idx] = f2bu(Sf[idx] + off);
  }
}

// ---------------- bf16 MFMA GEMM, 64x64 tile, ASYNC global_load_lds staging ----------------
// Chunk-swizzled unpadded LDS (2-way banks on b128 reads).
// MODE 0: Cb_z = bf16(acc) + Ct_z per-head transposed [bh][d][token], Qt/Kt pre-scaled by SC
// MODE 2: Cf += alpha*acc (fp32) and Cb0 = bf16(Cf), NSEG K-segments
// MODE 3: Cf = acc (fp32 only)
// MODE 4: Cf = acc and Cb0 = bf16(acc)
// MODE 5: Cb0 = bf16(acc)
// MODE 6: Cf = alpha*acc (overwrite) and Cb0 = bf16(alpha*acc)
template <int MODE, int NSEG>
__global__ __launch_bounds__(256) void gemm_mf(
    const ushort_t* __restrict__ A0, const ushort_t* __restrict__ A1, const ushort_t* __restrict__ A2,
    const ushort_t* __restrict__ B0, const ushort_t* __restrict__ B1, const ushort_t* __restrict__ B2,
    float* __restrict__ Cf,
    ushort_t* __restrict__ Cb0, ushort_t* __restrict__ Cb1, ushort_t* __restrict__ Cb2,
    ushort_t* __restrict__ Ct0, ushort_t* __restrict__ Ct1, ushort_t* __restrict__ Ct2,
    float alpha) {
  const int K = 1024;
  __shared__ __bf16 As[64][32];
  __shared__ __bf16 Bs[64][32];
  int tid = threadIdx.x;
  int m0 = blockIdx.y * 64, n0 = blockIdx.x * 64;

  const ushort_t* Bsel = B0;
  ushort_t* Cbz = Cb0;
  ushort_t* Ctz = Ct0;
  float tsc = 1.0f;
  if (MODE == 0) {
    int z = blockIdx.z;
    Bsel = (z == 0) ? B0 : (z == 1) ? B1 : B2;
    Cbz = (z == 0) ? Cb0 : (z == 1) ? Cb1 : Cb2;
    Ctz = (z == 0) ? Ct0 : (z == 1) ? Ct1 : Ct2;
    tsc = (z == 2) ? 1.0f : SC_C;   // Qt/Kt carry the 1/sqrt(d) factor
  }

  int lane = tid & 63, wave = tid >> 6;
  int wrow = wave >> 1, wcol = wave & 1;
  int fr = lane & 15, q = lane >> 4;

  int srow = wave * 16 + (lane >> 2);
  int scg = ((lane & 3) + (srow >> 1)) & 3;
  int scol = scg * 8;
  __bf16* ldsA = &As[wave * 16][0];
  __bf16* ldsB = &Bs[wave * 16][0];

  int rA0 = wrow * 32 + fr, rA1 = rA0 + 16;
  int rB0 = wcol * 32 + fr, rB1 = rB0 + 16;
  const bf16x8* pa0 = (const bf16x8*)&As[rA0][((q - (rA0 >> 1)) & 3) * 8];
  const bf16x8* pa1 = (const bf16x8*)&As[rA1][((q - (rA1 >> 1)) & 3) * 8];
  const bf16x8* pb0 = (const bf16x8*)&Bs[rB0][((q - (rB0 >> 1)) & 3) * 8];
  const bf16x8* pb1 = (const bf16x8*)&Bs[rB1][((q - (rB1 >> 1)) & 3) * 8];

  f32x4 acc[2][2] = {};

  #pragma unroll 1
  for (int seg = 0; seg < NSEG; seg++) {
    const ushort_t* Aseg = (seg == 0) ? A0 : (seg == 1) ? A1 : A2;
    const ushort_t* Bseg = (MODE == 0) ? Bsel : ((seg == 0) ? B0 : (seg == 1) ? B1 : B2);
    const ushort_t* ga = Aseg + (size_t)(m0 + srow) * K + scol;
    const ushort_t* gb = Bseg + (size_t)(n0 + srow) * K + scol;
    for (int k0 = 0; k0 < K; k0 += 32) {
      __syncthreads();
      async_cp16(ga + k0, ldsA);
      async_cp16(gb + k0, ldsB);
      __syncthreads();
      bf16x8 a0 = *pa0, a1 = *pa1, b0 = *pb0, b1 = *pb1;
      acc[0][0] = __builtin_amdgcn_mfma_f32_16x16x32_bf16(a0, b0, acc[0][0], 0, 0, 0);
      acc[0][1] = __builtin_amdgcn_mfma_f32_16x16x32_bf16(a0, b1, acc[0][1], 0, 0, 0);
      acc[1][0] = __builtin_amdgcn_mfma_f32_16x16x32_bf16(a1, b0, acc[1][0], 0, 0, 0);
      acc[1][1] = __builtin_amdgcn_mfma_f32_16x16x32_bf16(a1, b1, acc[1][1], 0, 0, 0);
    }
  }

  // C/D layout: col = lane&15, row = (lane>>4)*4 + reg
  #pragma unroll
  for (int mi = 0; mi < 2; mi++)
    #pragma unroll
    for (int ni = 0; ni < 2; ni++) {
      int col = n0 + wcol * 32 + ni * 16 + fr;
      int row0 = m0 + wrow * 32 + mi * 16 + q * 4;
      ushort_t pk[4];
      #pragma unroll
      for (int r = 0; r < 4; r++) {
        size_t idx = (size_t)(row0 + r) * E_DIM + col;
        float v = acc[mi][ni][r];
        if (MODE == 0) {
          Cbz[idx] = f2bu(v);
          pk[r] = f2bu(v * tsc);
        } else if (MODE == 2) {
          float nv = Cf[idx] + alpha * v;
          Cf[idx] = nv;
          Cb0[idx] = f2bu(nv);
        } else if (MODE == 3) {
          Cf[idx] = v;
        } else if (MODE == 4) {
          Cf[idx] = v;
          Cb0[idx] = f2bu(v);
        } else if (MODE == 6) {
          float nv = alpha * v;
          Cf[idx] = nv;
          Cb0[idx] = f2bu(nv);
        } else {  // MODE 5
          Cb0[idx] = f2bu(v);
        }
      }
      if (MODE == 0) {
        int hh = col >> 6, dd = col & 63;
        int bb = row0 >> 10, ss = row0 & 1023;
        *(uint2*)(Ctz + ((size_t)((bb * NH + hh) * HD + dd)) * S_LEN + ss) = *(uint2*)pk;
      }
    }
}

// ====================== MFMA attention, LDS-staged ======================

// ---- fused fwd: single-pass flash, log2-domain online softmax; emits m' = m + log2(l),
//      g=O-Xs (bf16 + transposed), Dv. grid (bh=32, y=16), balanced pairing. ----
__global__ __launch_bounds__(256) void fwd_fused(const ushort_t* __restrict__ Qg,
                                                 const ushort_t* __restrict__ Kg,
                                                 const ushort_t* __restrict__ Vt,
                                                 const float* __restrict__ Xs,
                                                 float* __restrict__ mbuf,
                                                 ushort_t* __restrict__ Gb,
                                                 ushort_t* __restrict__ Gt,
                                                 float* __restrict__ Dv) {
  int bh = blockIdx.x, y = blockIdx.y;
  int it = (y < 8) ? (15 - y) : (y - 8);
  int b = bh >> 4, h = bh & 15;
  int tid = threadIdx.x, lane = tid & 63, wv = tid >> 6;
  int fr = lane & 15, q = lane >> 4;
  int i0 = it * 64, band = wv * 16;
  __shared__ ushort_t Kts[64][72];  // [j][d]
  __shared__ ushort_t Vts[64][72];  // [d][j]
  __shared__ ushort_t Ps[64][72];   // [i][j] wave-private bands

  const ushort_t* Qrow = Qg + (size_t)(b * S_LEN + i0 + band + fr) * E_DIM + h * HD;
  bf16x8 aq0 = ldg8(Qrow + q * 8);
  bf16x8 aq1 = ldg8(Qrow + 32 + q * 8);

  float m[4], l[4];
  #pragma unroll
  for (int r = 0; r < 4; r++) { m[r] = -1e30f; l[r] = 0.f; }
  f32x4 oacc[4] = {};

  #pragma unroll 1
  for (int jt = 0; jt <= it; jt++) {
    int j0 = jt * 64;
    __syncthreads();
    #pragma unroll
    for (int t = 0; t < 2; t++) {
      int u = tid + 256 * t;
      int r = u >> 3, c8 = (u & 7) * 8;
      *(uint4*)&Kts[r][c8] = *(const uint4*)(Kg + (size_t)(b * S_LEN + j0 + r) * E_DIM + h * HD + c8);
      *(uint4*)&Vts[r][c8] = *(const uint4*)(Vt + (size_t)(bh * HD + r) * S_LEN + j0 + c8);
    }
    __syncthreads();
    f32x4 sA[4];
    #pragma unroll
    for (int nc = 0; nc < 4; nc++) {
      bf16x8 bk0 = *(const bf16x8*)&Kts[nc * 16 + fr][q * 8];
      bf16x8 bk1 = *(const bf16x8*)&Kts[nc * 16 + fr][32 + q * 8];
      f32x4 z = {};
      z = __builtin_amdgcn_mfma_f32_16x16x32_bf16(aq0, bk0, z, 0, 0, 0);
      sA[nc] = __builtin_amdgcn_mfma_f32_16x16x32_bf16(aq1, bk1, z, 0, 0, 0);
    }
    float sv[4][4];
    #pragma unroll
    for (int nc = 0; nc < 4; nc++)
      #pragma unroll
      for (int r = 0; r < 4; r++) {
        int row = i0 + band + q * 4 + r;
        int col = j0 + nc * 16 + fr;
        sv[nc][r] = (col <= row) ? sA[nc][r] * C2_C : -1e30f;  // log2 domain
      }
    #pragma unroll
    for (int r = 0; r < 4; r++) {
      float mx = fmaxf(fmaxf(sv[0][r], sv[1][r]), fmaxf(sv[2][r], sv[3][r]));
      #pragma unroll
      for (int off = 1; off < 16; off <<= 1) mx = fmaxf(mx, __shfl_xor(mx, off, 64));
      float mn = fmaxf(m[r], mx);
      float alpha = exp2f(m[r] - mn);
      float ps = 0.f;
      #pragma unroll
      for (int nc = 0; nc < 4; nc++) {
        float p = exp2f(sv[nc][r] - mn);
        Ps[band + q * 4 + r][nc * 16 + fr] = f2bu(p);
        ps += p;
      }
      #pragma unroll
      for (int off = 1; off < 16; off <<= 1) ps += __shfl_xor(ps, off, 64);
      l[r] = l[r] * alpha + ps;
      m[r] = mn;
      #pragma unroll
      for (int nc = 0; nc < 4; nc++) oacc[nc][r] *= alpha;
    }
    bf16x8 ap0 = *(const bf16x8*)&Ps[band + fr][q * 8];
    bf16x8 ap1 = *(const bf16x8*)&Ps[band + fr][32 + q * 8];
    #pragma unroll
    for (int nc = 0; nc < 4; nc++) {
      bf16x8 bv0 = *(const bf16x8*)&Vts[nc * 16 + fr][q * 8];
      bf16x8 bv1 = *(const bf16x8*)&Vts[nc * 16 + fr][32 + q * 8];
      oacc[nc] = __builtin_amdgcn_mfma_f32_16x16x32_bf16(ap0, bv0, oacc[nc], 0, 0, 0);
      oacc[nc] = __builtin_amdgcn_mfma_f32_16x16x32_bf16(ap1, bv1, oacc[nc], 0, 0, 0);
    }
  }
  // epilogue: g = O - Xs (bf16 normal + transposed), Dv partials
  float linv[4];
  #pragma unroll
  for (int r = 0; r < 4; r++) linv[r] = 1.0f / l[r];
  float dpart[4] = {};
  #pragma unroll
  for (int nc = 0; nc < 4; nc++) {
    ushort_t pg[4];
    #pragma unroll
    for (int r = 0; r < 4; r++) {
      int row = i0 + band + q * 4 + r;
      size_t gi = (size_t)(b * S_LEN + row) * E_DIM + h * HD + nc * 16 + fr;
      float o = oacc[nc][r] * linv[r];
      float g = o - Xs[gi];
      ushort_t bu = f2bu(g);
      Gb[gi] = bu;
      pg[r] = bu;
      dpart[r] += g * o;
    }
    int d = nc * 16 + fr;
    int s0 = i0 + band + q * 4;
    *(uint2*)(Gt + ((size_t)bh * HD + d) * S_LEN + s0) = *(uint2*)pg;
  }
  #pragma unroll
  for (int r = 0; r < 4; r++) {
    #pragma unroll
    for (int off = 1; off < 16; off <<= 1) dpart[r] += __shfl_xor(dpart[r], off, 64);
  }
  if (fr == 0) {
    #pragma unroll
    for (int r = 0; r < 4; r++) {
      size_t sid = (size_t)bh * S_LEN + i0 + band + q * 4 + r;
      mbuf[sid] = m[r] + log2f(l[r]);   // m' folds 1/l into the exponent
      Dv[sid] = dpart[r];
    }
  }
}

// ---- split backward, occupancy-first: grid (bh=32, y=32), 1024 independent blocks.
//      y even: dq for i-tile (15 - y/2) [longest first]; y odd: dk/dv for j-tile (y/2)
//      [longest first] -> LPT-interleaved dispatch. Per-iteration body IDENTICAL to the
//      merged kernel (2 barriers, same staging) — no added serial work. LDS = 5 swizzled
//      unpadded 64x64 tiles = 40960 B -> exactly 4 blocks/CU (16 waves/CU, 2x the merged
//      kernel's 8). dkdv shares one buffer for P then dS (wave-private overwrite). ----
__global__ __launch_bounds__(256, 4) void bwd_split(const ushort_t* __restrict__ Qg,
                                                    const ushort_t* __restrict__ Kg,
                                                    const ushort_t* __restrict__ Vg,
                                                    const ushort_t* __restrict__ Gg,
                                                    const ushort_t* __restrict__ Qt,
                                                    const ushort_t* __restrict__ Kt,
                                                    const ushort_t* __restrict__ Gt,
                                                    const float* __restrict__ mbuf,
                                                    const float* __restrict__ Dv,
                                                    ushort_t* __restrict__ GQ,
                                                    ushort_t* __restrict__ GK,
                                                    ushort_t* __restrict__ GV) {
  int bh = blockIdx.x, y = blockIdx.y;
  int b = bh >> 4, h = bh & 15;
  int tid = threadIdx.x, lane = tid & 63, wv = tid >> 6;
  int fr = lane & 15, q = lane >> 4;
  int band = wv * 16;
  __shared__ ushort_t sm[5][4096];   // 40960 B total

  if ((y & 1) == 0) {
    // ================= dq for i-tile (15 - y/2) =================
    int it = 15 - (y >> 1), i0 = it * 64;
    ushort_t* Ks = sm[0];   // [j][d]
    ushort_t* Vs = sm[1];   // [j][d]
    ushort_t* Ts = sm[2];   // [d][j] Kt (pre-scaled by SC)
    ushort_t* Ds = sm[3];   // dS wave-private bands

    const ushort_t* Qrow = Qg + (size_t)(b * S_LEN + i0 + band + fr) * E_DIM + h * HD;
    const ushort_t* Grow = Gg + (size_t)(b * S_LEN + i0 + band + fr) * E_DIM + h * HD;
    bf16x8 aq0 = ldg8(Qrow + q * 8), aq1 = ldg8(Qrow + 32 + q * 8);
    bf16x8 ag0 = ldg8(Grow + q * 8), ag1 = ldg8(Grow + 32 + q * 8);

    float mrow[4], Dr[4];
    #pragma unroll
    for (int r = 0; r < 4; r++) {
      size_t sid = (size_t)bh * S_LEN + i0 + band + q * 4 + r;
      mrow[r] = mbuf[sid]; Dr[r] = Dv[sid];
    }
    f32x4 dqacc[4] = {};

    #pragma unroll 1
    for (int jt = 0; jt <= it; jt++) {
      int j0 = jt * 64;
      __syncthreads();
      #pragma unroll
      for (int t = 0; t < 2; t++) {
        int u = tid + 256 * t;
        int r = u >> 3, c8 = (u & 7) * 8;
        int d = swz(r, c8);
        *(uint4*)&Ks[d] = *(const uint4*)(Kg + (size_t)(b * S_LEN + j0 + r) * E_DIM + h * HD + c8);
        *(uint4*)&Vs[d] = *(const uint4*)(Vg + (size_t)(b * S_LEN + j0 + r) * E_DIM + h * HD + c8);
        *(uint4*)&Ts[d] = *(const uint4*)(Kt + (size_t)(bh * HD + r) * S_LEN + j0 + c8);
      }
      __syncthreads();
      f32x4 sA[4], dpA[4];
      #pragma unroll
      for (int nc = 0; nc < 4; nc++) {
        bf16x8 bk0 = *(const bf16x8*)&Ks[swz(nc * 16 + fr, q * 8)];
        bf16x8 bk1 = *(const bf16x8*)&Ks[swz(nc * 16 + fr, 32 + q * 8)];
        bf16x8 bv0 = *(const bf16x8*)&Vs[swz(nc * 16 + fr, q * 8)];
        bf16x8 bv1 = *(const bf16x8*)&Vs[swz(nc * 16 + fr, 32 + q * 8)];
        f32x4 z = {};
        z = __builtin_amdgcn_mfma_f32_16x16x32_bf16(aq0, bk0, z, 0, 0, 0);
        sA[nc] = __builtin_amdgcn_mfma_f32_16x16x32_bf16(aq1, bk1, z, 0, 0, 0);
        f32x4 z2 = {};
        z2 = __builtin_amdgcn_mfma_f32_16x16x32_bf16(ag0, bv0, z2, 0, 0, 0);
        dpA[nc] = __builtin_amdgcn_mfma_f32_16x16x32_bf16(ag1, bv1, z2, 0, 0, 0);
      }
      #pragma unroll
      for (int nc = 0; nc < 4; nc++)
        #pragma unroll
        for (int r = 0; r < 4; r++) {
          int row = i0 + band + q * 4 + r;
          int col = j0 + nc * 16 + fr;
          float ds = 0.f;
          if (col <= row) {
            float P = exp2f(fmaf(sA[nc][r], C2_C, -mrow[r]));
            ds = P * (dpA[nc][r] - Dr[r]);   // SC lives in Kt
          }
          Ds[swz(band + q * 4 + r, nc * 16 + fr)] = f2bu(ds);  // wave-private
        }
      bf16x8 ad0 = *(const bf16x8*)&Ds[swz(band + fr, q * 8)];
      bf16x8 ad1 = *(const bf16x8*)&Ds[swz(band + fr, 32 + q * 8)];
      #pragma unroll
      for (int nc = 0; nc < 4; nc++) {
        bf16x8 bt0 = *(const bf16x8*)&Ts[swz(nc * 16 + fr, q * 8)];
        bf16x8 bt1 = *(const bf16x8*)&Ts[swz(nc * 16 + fr, 32 + q * 8)];
        dqacc[nc] = __builtin_amdgcn_mfma_f32_16x16x32_bf16(ad0, bt0, dqacc[nc], 0, 0, 0);
        dqacc[nc] = __builtin_amdgcn_mfma_f32_16x16x32_bf16(ad1, bt1, dqacc[nc], 0, 0, 0);
      }
    }
    #pragma unroll
    for (int nc = 0; nc < 4; nc++)
      #pragma unroll
      for (int r = 0; r < 4; r++) {
        int row = i0 + band + q * 4 + r;
        size_t gi = (size_t)(b * S_LEN + row) * E_DIM + h * HD + nc * 16 + fr;
        GQ[gi] = f2bu(dqacc[nc][r]);
      }
  } else {
    // ================= dk/dv for j-tile (y/2) =================
    int jt = y >> 1, j0 = jt * 64;
    ushort_t* Qs  = sm[0];  // [i][d]
    ushort_t* Gs  = sm[1];  // [i][d]
    ushort_t* Qts = sm[2];  // [d][i] (pre-scaled by SC)
    ushort_t* Gts = sm[3];  // [d][i]
    ushort_t* Ps  = sm[4];  // P then dS (wave-private rows, in-order per-wave DS)

    const ushort_t* Krow = Kg + (size_t)(b * S_LEN + j0 + band + fr) * E_DIM + h * HD;
    const ushort_t* Vrow = Vg + (size_t)(b * S_LEN + j0 + band + fr) * E_DIM + h * HD;
    bf16x8 ak0 = ldg8(Krow + q * 8), ak1 = ldg8(Krow + 32 + q * 8);
    bf16x8 av0 = ldg8(Vrow + q * 8), av1 = ldg8(Vrow + 32 + q * 8);

    f32x4 dkacc[4] = {}, dvacc[4] = {};

    #pragma unroll 1
    for (int i_t = jt; i_t < 16; i_t++) {
      int i0 = i_t * 64;
      __syncthreads();
      #pragma unroll
      for (int t = 0; t < 2; t++) {
        int u = tid + 256 * t;
        int r = u >> 3, c8 = (u & 7) * 8;
        int d = swz(r, c8);
        *(uint4*)&Qs[d]  = *(const uint4*)(Qg + (size_t)(b * S_LEN + i0 + r) * E_DIM + h * HD + c8);
        *(uint4*)&Gs[d]  = *(const uint4*)(Gg + (size_t)(b * S_LEN + i0 + r) * E_DIM + h * HD + c8);
        *(uint4*)&Qts[d] = *(const uint4*)(Qt + (size_t)(bh * HD + r) * S_LEN + i0 + c8);
        *(uint4*)&Gts[d] = *(const uint4*)(Gt + (size_t)(bh * HD + r) * S_LEN + i0 + c8);
      }
      __syncthreads();
      float mc[4], Dc[4];
      #pragma unroll
      for (int nc = 0; nc < 4; nc++) {
        size_t sid = (size_t)bh * S_LEN + i0 + nc * 16 + fr;
        mc[nc] = mbuf[sid]; Dc[nc] = Dv[sid];
      }
      f32x4 stA[4], dptA[4];
      #pragma unroll
      for (int nc = 0; nc < 4; nc++) {
        bf16x8 bq0 = *(const bf16x8*)&Qs[swz(nc * 16 + fr, q * 8)];
        bf16x8 bq1 = *(const bf16x8*)&Qs[swz(nc * 16 + fr, 32 + q * 8)];
        bf16x8 bg0 = *(const bf16x8*)&Gs[swz(nc * 16 + fr, q * 8)];
        bf16x8 bg1 = *(const bf16x8*)&Gs[swz(nc * 16 + fr, 32 + q * 8)];
        f32x4 z = {};
        z = __builtin_amdgcn_mfma_f32_16x16x32_bf16(ak0, bq0, z, 0, 0, 0);
        stA[nc] = __builtin_amdgcn_mfma_f32_16x16x32_bf16(ak1, bq1, z, 0, 0, 0);
        f32x4 z2 = {};
        z2 = __builtin_amdgcn_mfma_f32_16x16x32_bf16(av0, bg0, z2, 0, 0, 0);
        dptA[nc] = __builtin_amdgcn_mfma_f32_16x16x32_bf16(av1, bg1, z2, 0, 0, 0);
      }
      ushort_t dsp[4][4];
      #pragma unroll
      for (int nc = 0; nc < 4; nc++)
        #pragma unroll
        for (int r = 0; r < 4; r++) {
          int jrow = j0 + band + q * 4 + r;
          int icol = i0 + nc * 16 + fr;
          float P = 0.f, ds = 0.f;
          if (icol >= jrow) {
            P = exp2f(fmaf(stA[nc][r], C2_C, -mc[nc]));
            ds = P * (dptA[nc][r] - Dc[nc]);   // SC lives in Qt
          }
          dsp[nc][r] = f2bu(ds);
          Ps[swz(band + q * 4 + r, nc * 16 + fr)] = f2bu(P);   // wave-private
        }
      bf16x8 ap0 = *(const bf16x8*)&Ps[swz(band + fr, q * 8)];
      bf16x8 ap1 = *(const bf16x8*)&Ps[swz(band + fr, 32 + q * 8)];
      #pragma unroll
      for (int nc = 0; nc < 4; nc++) {
        bf16x8 bg0 = *(const bf16x8*)&Gts[swz(nc * 16 + fr, q * 8)];
        bf16x8 bg1 = *(const bf16x8*)&Gts[swz(nc * 16 + fr, 32 + q * 8)];
        dvacc[nc] = __builtin_amdgcn_mfma_f32_16x16x32_bf16(ap0, bg0, dvacc[nc], 0, 0, 0);
        dvacc[nc] = __builtin_amdgcn_mfma_f32_16x16x32_bf16(ap1, bg1, dvacc[nc], 0, 0, 0);
      }
      // overwrite the P buffer with dS (wave-private; per-wave DS ordering
      // guarantees the ap reads above complete first)
      #pragma unroll
      for (int nc = 0; nc < 4; nc++)
        #pragma unroll
        for (int r = 0; r < 4; r++)
          Ps[swz(band + q * 4 + r, nc * 16 + fr)] = dsp[nc][r];
      bf16x8 ad0 = *(const bf16x8*)&Ps[swz(band + fr, q * 8)];
      bf16x8 ad1 = *(const bf16x8*)&Ps[swz(band + fr, 32 + q * 8)];
      #pragma unroll
      for (int nc = 0; nc < 4; nc++) {
        bf16x8 bq0 = *(const bf16x8*)&Qts[swz(nc * 16 + fr, q * 8)];
        bf16x8 bq1 = *(const bf16x8*)&Qts[swz(nc * 16 + fr, 32 + q * 8)];
        dkacc[nc] = __builtin_amdgcn_mfma_f32_16x16x32_bf16(ad0, bq0, dkacc[nc], 0, 0, 0);
        dkacc[nc] = __builtin_amdgcn_mfma_f32_16x16x32_bf16(ad1, bq1, dkacc[nc], 0, 0, 0);
      }
    }
    #pragma unroll
    for (int nc = 0; nc < 4; nc++)
      #pragma unroll
      for (int r = 0; r < 4; r++) {
        int jrow = j0 + band + q * 4 + r;
        size_t gi = (size_t)(b * S_LEN + jrow) * E_DIM + h * HD + nc * 16 + fr;
        GK[gi] = f2bu(dkacc[nc][r]);
        GV[gi] = f2bu(dvacc[nc][r]);
      }
  }
}

// ---------------- launch ----------------
extern "C" void kernel_launch(void* const* d_in, const int* in_sizes, int n_in,
                              void* d_out, int out_size, void* d_ws, size_t ws_size,
                              hipStream_t stream) {
  const float* T1 = (const float*)d_in[0];
  const float* Wq = (const float*)d_in[1];
  const float* Wk = (const float*)d_in[2];
  const float* Wv = (const float*)d_in[3];
  const float* Wo = (const float*)d_in[4];

  const size_t M2 = 2097152;   // 2048*1024
  const size_t M1 = 1048576;
  float* w = (float*)d_ws;
  float* Xs = w;                       // 8 MB fp32 target
  float* mS = Xs + M2;                 // 64K f32 (stores m')
  float* DvS = mS + 65536;
  ushort_t* u = (ushort_t*)(DvS + 65536);
  ushort_t* W0 = u;          ushort_t* W1 = W0 + M1;  ushort_t* W2 = W1 + M1;
  ushort_t* W3 = W2 + M1;    ushort_t* W4 = W3 + M1;  ushort_t* W5 = W4 + M1;
  ushort_t* Qb = W5 + M1;    ushort_t* Kb = Qb + M2;  ushort_t* Vb = Kb + M2;
  ushort_t* Qt = Vb + M2;    ushort_t* Kt = Qt + M2;  ushort_t* Vt = Kt + M2;
  ushort_t* Gt = Vt + M2;
  ushort_t* Gb = Gt + M2;
  ushort_t* GQb = Gb + M2;   ushort_t* GKb = GQb + M2; ushort_t* GVb = GKb + M2;
  ushort_t* X2b = GVb + M2;
  float* X2 = (float*)d_out;

  // stage-1 aliases (all overwritten before stage-2 uses the slots)
  float* Mf  = (float*)Qb;       // 4 MB
  float* M2f = (float*)Kb;       // 4 MB
  ushort_t* Mb  = Gt;            // 2 MB
  ushort_t* Nb  = Vb;            // 2 MB
  ushort_t* AtB = Qt;            // 2 MB
  ushort_t* T1b = Kt;            // 4 MB

  // iter-1 shortcut aliases (dead before their regions' stage-2 consumers)
  float* Sf  = (float*)GQb;      // 8 MB fp32 scan partials (spans GQb+GKb)
  float* tot = mS;               // 128 KB chunk totals (mS rewritten by fwd of iter 2)
  ushort_t* Sb = GVb;            // 4 MB bf16 scan result

  dim3 pgrid(16, 16);
  dim3 sgrid(16, 16);       // 1024x1024 GEMMs
  dim3 ggrid(16, 32);       // 2048x1024 GEMMs
  dim3 ggrid3(16, 32, 3);   // QKV
  dim3 agrid(BH_CNT, 16);   // fwd attention
  dim3 bgrid(BH_CNT, 32);   // split bwd attention (LPT-interleaved dq/dkdv blocks)

  // ---- stage 1 (algebraic): Xs = T * Wo * (3LR·I - 3LR²·M + LR³·M²),  M = WoᵀWo ----
  k_cast<<<(M2 / 4 + 255) / 256, 256, 0, stream>>>(T1, T1b, (int)(M2 / 4));
  prep_w<<<pgrid, 256, 0, stream>>>(Wo, W0, W1);
  // M = W1·W1ᵀ  (fp32 + bf16)
  gemm_mf<4, 1><<<sgrid, 256, 0, stream>>>(W1, nullptr, nullptr, W1, nullptr, nullptr,
                                           Mf, Mb, nullptr, nullptr,
                                           nullptr, nullptr, nullptr, 0.f);
  // M2 = Mb·Mbᵀ (M symmetric)
  gemm_mf<3, 1><<<sgrid, 256, 0, stream>>>(Mb, nullptr, nullptr, Mb, nullptr, nullptr,
                                           M2f, nullptr, nullptr, nullptr,
                                           nullptr, nullptr, nullptr, 0.f);
  k_formN<<<(M1 + 255) / 256, 256, 0, stream>>>(Mf, M2f, Nb);
  // AtB = N·Woᵀ  (symmetric N; this is (Wo·N)ᵀ in [N,K] form)
  gemm_mf<5, 1><<<sgrid, 256, 0, stream>>>(Nb, nullptr, nullptr, W0, nullptr, nullptr,
                                           nullptr, AtB, nullptr, nullptr,
                                           nullptr, nullptr, nullptr, 0.f);
  // stage-2 weights (W0/W1 free after AtB)
  prep_w<<<pgrid, 256, 0, stream>>>(Wq, W0, W3);
  prep_w<<<pgrid, 256, 0, stream>>>(Wk, W1, W4);
  prep_w<<<pgrid, 256, 0, stream>>>(Wv, W2, W5);
  // Xs = T1b·AtBᵀ (fp32)
  gemm_mf<3, 1><<<ggrid, 256, 0, stream>>>(T1b, nullptr, nullptr, AtB, nullptr, nullptr,
                                           Xs, nullptr, nullptr, nullptr,
                                           nullptr, nullptr, nullptr, 0.f);

  // ---- stage 2, iteration 1 (closed form): x=0 => Q=K=V=0, P exactly causal-uniform,
  //      dQ=dK=0, dV = P0^T(-Xs); x1 = LR * (P0^T Xs) * Wv via fp32 suffix scan + one GEMM ----
  k_scan1<<<dim3(E_DIM / 256, 2, 16), 256, 0, stream>>>(Xs, Sf, tot);
  k_scan2<<<dim3(E_DIM / 256, 2, 16), 256, 0, stream>>>(Sf, tot, Sb);
  gemm_mf<6, 1><<<ggrid, 256, 0, stream>>>(Sb, nullptr, nullptr, W5, nullptr, nullptr,
                                           X2, X2b, nullptr, nullptr,
                                           nullptr, nullptr, nullptr, LR_C);

  // ---- stage 2, iterations 2..3 (full PC gradient) ----
  for (int t = 1; t < 3; t++) {
    gemm_mf<0, 1><<<ggrid3, 256, 0, stream>>>(X2b, nullptr, nullptr, W0, W1, W2,
                                              nullptr, Qb, Kb, Vb,
                                              Qt, Kt, Vt, 0.f);
    fwd_fused<<<agrid, 256, 0, stream>>>(Qb, Kb, Vt, Xs, mS, Gb, Gt, DvS);
    bwd_split<<<bgrid, 256, 0, stream>>>(Qb, Kb, Vb, Gb, Qt, Kt, Gt, mS, DvS,
                                         GQb, GKb, GVb);
    gemm_mf<2, 3><<<ggrid, 256, 0, stream>>>(GQb, GKb, GVb, W3, W4, W5,
                                             X2, X2b, nullptr, nullptr,
                                             nullptr, nullptr, nullptr, -LR_C);
  }
}

// Round 5
// 445.490 us; speedup vs baseline: 1.1894x; 1.1894x over previous
//
#include <hip/hip_runtime.h>
#include <hip/hip_bf16.h>
#include <math.h>

// Problem constants (B=2, S=1024, E=1024, H=16, D=64)
#define S_LEN 1024
#define E_DIM 1024
#define NH 16
#define HD 64
#define M_ROWS 2048   // B*S
#define BH_CNT 32     // B*NH

static constexpr float LR_C = 0.01f;
static constexpr float SC_C = 0.125f;                // 1/sqrt(64)
static constexpr float C2_C = 0.125f * 1.44269504f;  // SC * log2(e): log2-domain softmax

typedef unsigned short ushort_t;
typedef __attribute__((ext_vector_type(8))) __bf16 bf16x8;
typedef __attribute__((ext_vector_type(4))) float f32x4;

static __device__ inline ushort_t f2bu(float f) {
  __hip_bfloat16 h = __float2bfloat16(f);
  return *(ushort_t*)&h;
}
static __device__ inline bf16x8 ldg8(const ushort_t* p) { return *(const bf16x8*)p; }

// async global->LDS, 16B per lane; LDS dest = wave-uniform base + lane*16
static __device__ inline void async_cp16(const ushort_t* g, __bf16* lds_wave_base) {
  __builtin_amdgcn_global_load_lds((const __attribute__((address_space(1))) void*)g,
                                   (__attribute__((address_space(3))) void*)lds_wave_base,
                                   16, 0, 0);
}

// ---------------- weight prep: bf16 cast + bf16 transpose, 64x64 tiles ----------------
__global__ __launch_bounds__(256) void prep_w(const float* __restrict__ W,
                                              ushort_t* __restrict__ Wb,
                                              ushort_t* __restrict__ WTb) {
  __shared__ float ts[64][65];
  int bx = blockIdx.x * 64, by = blockIdx.y * 64;
  int t = threadIdx.x;
  int rr = t >> 6, cc = t & 63;
  #pragma unroll
  for (int p = 0; p < 16; p++) {
    int r = p * 4 + rr;
    float v = W[(size_t)(by + r) * E_DIM + bx + cc];
    ts[r][cc] = v;
    Wb[(size_t)(by + r) * E_DIM + bx + cc] = f2bu(v);
  }
  __syncthreads();
  #pragma unroll
  for (int p = 0; p < 16; p++) {
    int r = p * 4 + rr;
    WTb[(size_t)(bx + r) * E_DIM + by + cc] = f2bu(ts[cc][r]);
  }
}

// ---------------- fp32 -> bf16 cast (float4-wide) ----------------
__global__ __launch_bounds__(256) void k_cast(const float* __restrict__ in,
                                              ushort_t* __restrict__ out, int n4) {
  int i = blockIdx.x * 256 + threadIdx.x;
  if (i < n4) {
    float4 v = ((const float4*)in)[i];
    ushort_t p[4] = {f2bu(v.x), f2bu(v.y), f2bu(v.z), f2bu(v.w)};
    *(uint2*)(out + (size_t)i * 4) = *(uint2*)p;
  }
}

// ---------------- N = 3LR*I - 3LR^2*M + LR^3*M2  (bf16 out) ----------------
__global__ __launch_bounds__(256) void k_formN(const float* __restrict__ Mf,
                                               const float* __restrict__ M2f,
                                               ushort_t* __restrict__ Nb) {
  int idx = blockIdx.x * 256 + threadIdx.x;   // 1M elements
  int i = idx >> 10, j = idx & 1023;
  float v = -3.f * LR_C * LR_C * Mf[idx] + LR_C * LR_C * LR_C * M2f[idx];
  if (i == j) v += 3.f * LR_C;
  Nb[idx] = f2bu(v);
}

// ---------------- iter-1 shortcut: suffix scan S[j] = sum_{i>=j} Xs[i]/(i+1) ----------------
// x=0 => Q=K=V=0 => P is exactly causal-uniform, dQ=dK=0, dV = P0^T(-Xs).
// x1 = LR * (P0^T Xs) * Wv. Two-pass chunked scan over the sequence dim.
__global__ __launch_bounds__(256) void k_scan1(const float* __restrict__ Xs,
                                               float* __restrict__ Sf,
                                               float* __restrict__ tot) {
  int e = blockIdx.x * 256 + threadIdx.x;  // column 0..1023
  int b = blockIdx.y;                      // batch
  int z = blockIdx.z;                      // chunk 0..15 (64 rows each)
  float acc = 0.f;
  for (int i = z * 64 + 63; i >= z * 64; i--) {
    size_t idx = ((size_t)b * S_LEN + i) * E_DIM + e;
    acc = fmaf(Xs[idx], 1.0f / (float)(i + 1), acc);
    Sf[idx] = acc;
  }
  tot[((size_t)b * 16 + z) * E_DIM + e] = acc;
}

__global__ __launch_bounds__(256) void k_scan2(const float* __restrict__ Sf,
                                               const float* __restrict__ tot,
                                               ushort_t* __restrict__ Sb) {
  int e = blockIdx.x * 256 + threadIdx.x;
  int b = blockIdx.y;
  int z = blockIdx.z;
  float off = 0.f;
  for (int c = z + 1; c < 16; c++) off += tot[((size_t)b * 16 + c) * E_DIM + e];
  for (int i = z * 64; i < z * 64 + 64; i++) {
    size_t idx = ((size_t)b * S_LEN + i) * E_DIM + e;
    Sb[idx] = f2bu(Sf[idx] + off);
  }
}

// ---------------- bf16 MFMA GEMM, 64x64 tile, BK=64, ASYNC global_load_lds staging ----------
// Four 4KB half-buffers (16KB LDS); 16 barrier-drains per K=1024 (was 32 at BK=32):
// per drain now 8 MFMAs/wave instead of 4 — halves the dominant barrier-drain stall.
// k-halves accumulated h0 then h1 = identical order to BK=32 -> bit-identical results.
// Chunk-swizzled unpadded LDS (2-way banks on b128 reads).
// MODE 0: Cb_z = bf16(acc) + Ct_z per-head transposed [bh][d][token], Qt/Kt pre-scaled by SC
// MODE 2: Cf += alpha*acc (fp32) and Cb0 = bf16(Cf), NSEG K-segments
// MODE 3: Cf = acc (fp32 only)
// MODE 4: Cf = acc and Cb0 = bf16(acc)
// MODE 5: Cb0 = bf16(acc)
// MODE 6: Cf = alpha*acc (overwrite) and Cb0 = bf16(alpha*acc)
template <int MODE, int NSEG>
__global__ __launch_bounds__(256) void gemm_mf(
    const ushort_t* __restrict__ A0, const ushort_t* __restrict__ A1, const ushort_t* __restrict__ A2,
    const ushort_t* __restrict__ B0, const ushort_t* __restrict__ B1, const ushort_t* __restrict__ B2,
    float* __restrict__ Cf,
    ushort_t* __restrict__ Cb0, ushort_t* __restrict__ Cb1, ushort_t* __restrict__ Cb2,
    ushort_t* __restrict__ Ct0, ushort_t* __restrict__ Ct1, ushort_t* __restrict__ Ct2,
    float alpha) {
  const int K = 1024;
  __shared__ __bf16 As0[64][32];
  __shared__ __bf16 As1[64][32];
  __shared__ __bf16 Bs0[64][32];
  __shared__ __bf16 Bs1[64][32];
  int tid = threadIdx.x;
  int m0 = blockIdx.y * 64, n0 = blockIdx.x * 64;

  const ushort_t* Bsel = B0;
  ushort_t* Cbz = Cb0;
  ushort_t* Ctz = Ct0;
  float tsc = 1.0f;
  if (MODE == 0) {
    int z = blockIdx.z;
    Bsel = (z == 0) ? B0 : (z == 1) ? B1 : B2;
    Cbz = (z == 0) ? Cb0 : (z == 1) ? Cb1 : Cb2;
    Ctz = (z == 0) ? Ct0 : (z == 1) ? Ct1 : Ct2;
    tsc = (z == 2) ? 1.0f : SC_C;   // Qt/Kt carry the 1/sqrt(d) factor
  }

  int lane = tid & 63, wave = tid >> 6;
  int wrow = wave >> 1, wcol = wave & 1;
  int fr = lane & 15, q = lane >> 4;

  int srow = wave * 16 + (lane >> 2);
  int scg = ((lane & 3) + (srow >> 1)) & 3;
  int scol = scg * 8;
  __bf16* ldsA0 = &As0[wave * 16][0];
  __bf16* ldsA1 = &As1[wave * 16][0];
  __bf16* ldsB0 = &Bs0[wave * 16][0];
  __bf16* ldsB1 = &Bs1[wave * 16][0];

  int rA0 = wrow * 32 + fr, rA1r = rA0 + 16;
  int rB0 = wcol * 32 + fr, rB1r = rB0 + 16;
  int cA0 = ((q - (rA0 >> 1)) & 3) * 8;
  int cA1 = ((q - (rA1r >> 1)) & 3) * 8;
  int cB0 = ((q - (rB0 >> 1)) & 3) * 8;
  int cB1 = ((q - (rB1r >> 1)) & 3) * 8;
  const bf16x8* pa0h0 = (const bf16x8*)&As0[rA0][cA0];
  const bf16x8* pa0h1 = (const bf16x8*)&As1[rA0][cA0];
  const bf16x8* pa1h0 = (const bf16x8*)&As0[rA1r][cA1];
  const bf16x8* pa1h1 = (const bf16x8*)&As1[rA1r][cA1];
  const bf16x8* pb0h0 = (const bf16x8*)&Bs0[rB0][cB0];
  const bf16x8* pb0h1 = (const bf16x8*)&Bs1[rB0][cB0];
  const bf16x8* pb1h0 = (const bf16x8*)&Bs0[rB1r][cB1];
  const bf16x8* pb1h1 = (const bf16x8*)&Bs1[rB1r][cB1];

  f32x4 acc[2][2] = {};

  #pragma unroll 1
  for (int seg = 0; seg < NSEG; seg++) {
    const ushort_t* Aseg = (seg == 0) ? A0 : (seg == 1) ? A1 : A2;
    const ushort_t* Bseg = (MODE == 0) ? Bsel : ((seg == 0) ? B0 : (seg == 1) ? B1 : B2);
    const ushort_t* ga = Aseg + (size_t)(m0 + srow) * K + scol;
    const ushort_t* gb = Bseg + (size_t)(n0 + srow) * K + scol;
    #pragma unroll 1
    for (int k0 = 0; k0 < K; k0 += 64) {
      __syncthreads();
      async_cp16(ga + k0, ldsA0);
      async_cp16(ga + k0 + 32, ldsA1);
      async_cp16(gb + k0, ldsB0);
      async_cp16(gb + k0 + 32, ldsB1);
      __syncthreads();
      bf16x8 a00 = *pa0h0, a01 = *pa0h1, a10 = *pa1h0, a11 = *pa1h1;
      bf16x8 b00 = *pb0h0, b01 = *pb0h1, b10 = *pb1h0, b11 = *pb1h1;
      acc[0][0] = __builtin_amdgcn_mfma_f32_16x16x32_bf16(a00, b00, acc[0][0], 0, 0, 0);
      acc[0][1] = __builtin_amdgcn_mfma_f32_16x16x32_bf16(a00, b10, acc[0][1], 0, 0, 0);
      acc[1][0] = __builtin_amdgcn_mfma_f32_16x16x32_bf16(a10, b00, acc[1][0], 0, 0, 0);
      acc[1][1] = __builtin_amdgcn_mfma_f32_16x16x32_bf16(a10, b10, acc[1][1], 0, 0, 0);
      acc[0][0] = __builtin_amdgcn_mfma_f32_16x16x32_bf16(a01, b01, acc[0][0], 0, 0, 0);
      acc[0][1] = __builtin_amdgcn_mfma_f32_16x16x32_bf16(a01, b11, acc[0][1], 0, 0, 0);
      acc[1][0] = __builtin_amdgcn_mfma_f32_16x16x32_bf16(a11, b01, acc[1][0], 0, 0, 0);
      acc[1][1] = __builtin_amdgcn_mfma_f32_16x16x32_bf16(a11, b11, acc[1][1], 0, 0, 0);
    }
  }

  // C/D layout: col = lane&15, row = (lane>>4)*4 + reg
  #pragma unroll
  for (int mi = 0; mi < 2; mi++)
    #pragma unroll
    for (int ni = 0; ni < 2; ni++) {
      int col = n0 + wcol * 32 + ni * 16 + fr;
      int row0 = m0 + wrow * 32 + mi * 16 + q * 4;
      ushort_t pk[4];
      #pragma unroll
      for (int r = 0; r < 4; r++) {
        size_t idx = (size_t)(row0 + r) * E_DIM + col;
        float v = acc[mi][ni][r];
        if (MODE == 0) {
          Cbz[idx] = f2bu(v);
          pk[r] = f2bu(v * tsc);
        } else if (MODE == 2) {
          float nv = Cf[idx] + alpha * v;
          Cf[idx] = nv;
          Cb0[idx] = f2bu(nv);
        } else if (MODE == 3) {
          Cf[idx] = v;
        } else if (MODE == 4) {
          Cf[idx] = v;
          Cb0[idx] = f2bu(v);
        } else if (MODE == 6) {
          float nv = alpha * v;
          Cf[idx] = nv;
          Cb0[idx] = f2bu(nv);
        } else {  // MODE 5
          Cb0[idx] = f2bu(v);
        }
      }
      if (MODE == 0) {
        int hh = col >> 6, dd = col & 63;
        int bb = row0 >> 10, ss = row0 & 1023;
        *(uint2*)(Ctz + ((size_t)((bb * NH + hh) * HD + dd)) * S_LEN + ss) = *(uint2*)pk;
      }
    }
}

// ====================== MFMA attention, LDS-staged ======================

// ---- fused fwd: single-pass flash, log2-domain online softmax; emits m' = m + log2(l),
//      g=O-Xs (bf16 + transposed), Dv. grid (bh=32, y=16), balanced pairing. ----
__global__ __launch_bounds__(256) void fwd_fused(const ushort_t* __restrict__ Qg,
                                                 const ushort_t* __restrict__ Kg,
                                                 const ushort_t* __restrict__ Vt,
                                                 const float* __restrict__ Xs,
                                                 float* __restrict__ mbuf,
                                                 ushort_t* __restrict__ Gb,
                                                 ushort_t* __restrict__ Gt,
                                                 float* __restrict__ Dv) {
  int bh = blockIdx.x, y = blockIdx.y;
  int it = (y < 8) ? (15 - y) : (y - 8);
  int b = bh >> 4, h = bh & 15;
  int tid = threadIdx.x, lane = tid & 63, wv = tid >> 6;
  int fr = lane & 15, q = lane >> 4;
  int i0 = it * 64, band = wv * 16;
  __shared__ ushort_t Kts[64][72];  // [j][d]
  __shared__ ushort_t Vts[64][72];  // [d][j]
  __shared__ ushort_t Ps[64][72];   // [i][j] wave-private bands

  const ushort_t* Qrow = Qg + (size_t)(b * S_LEN + i0 + band + fr) * E_DIM + h * HD;
  bf16x8 aq0 = ldg8(Qrow + q * 8);
  bf16x8 aq1 = ldg8(Qrow + 32 + q * 8);

  float m[4], l[4];
  #pragma unroll
  for (int r = 0; r < 4; r++) { m[r] = -1e30f; l[r] = 0.f; }
  f32x4 oacc[4] = {};

  #pragma unroll 1
  for (int jt = 0; jt <= it; jt++) {
    int j0 = jt * 64;
    __syncthreads();
    #pragma unroll
    for (int t = 0; t < 2; t++) {
      int u = tid + 256 * t;
      int r = u >> 3, c8 = (u & 7) * 8;
      *(uint4*)&Kts[r][c8] = *(const uint4*)(Kg + (size_t)(b * S_LEN + j0 + r) * E_DIM + h * HD + c8);
      *(uint4*)&Vts[r][c8] = *(const uint4*)(Vt + (size_t)(bh * HD + r) * S_LEN + j0 + c8);
    }
    __syncthreads();
    f32x4 sA[4];
    #pragma unroll
    for (int nc = 0; nc < 4; nc++) {
      bf16x8 bk0 = *(const bf16x8*)&Kts[nc * 16 + fr][q * 8];
      bf16x8 bk1 = *(const bf16x8*)&Kts[nc * 16 + fr][32 + q * 8];
      f32x4 z = {};
      z = __builtin_amdgcn_mfma_f32_16x16x32_bf16(aq0, bk0, z, 0, 0, 0);
      sA[nc] = __builtin_amdgcn_mfma_f32_16x16x32_bf16(aq1, bk1, z, 0, 0, 0);
    }
    float sv[4][4];
    #pragma unroll
    for (int nc = 0; nc < 4; nc++)
      #pragma unroll
      for (int r = 0; r < 4; r++) {
        int row = i0 + band + q * 4 + r;
        int col = j0 + nc * 16 + fr;
        sv[nc][r] = (col <= row) ? sA[nc][r] * C2_C : -1e30f;  // log2 domain
      }
    #pragma unroll
    for (int r = 0; r < 4; r++) {
      float mx = fmaxf(fmaxf(sv[0][r], sv[1][r]), fmaxf(sv[2][r], sv[3][r]));
      #pragma unroll
      for (int off = 1; off < 16; off <<= 1) mx = fmaxf(mx, __shfl_xor(mx, off, 64));
      float mn = fmaxf(m[r], mx);
      float alpha = exp2f(m[r] - mn);
      float ps = 0.f;
      #pragma unroll
      for (int nc = 0; nc < 4; nc++) {
        float p = exp2f(sv[nc][r] - mn);
        Ps[band + q * 4 + r][nc * 16 + fr] = f2bu(p);
        ps += p;
      }
      #pragma unroll
      for (int off = 1; off < 16; off <<= 1) ps += __shfl_xor(ps, off, 64);
      l[r] = l[r] * alpha + ps;
      m[r] = mn;
      #pragma unroll
      for (int nc = 0; nc < 4; nc++) oacc[nc][r] *= alpha;
    }
    bf16x8 ap0 = *(const bf16x8*)&Ps[band + fr][q * 8];
    bf16x8 ap1 = *(const bf16x8*)&Ps[band + fr][32 + q * 8];
    #pragma unroll
    for (int nc = 0; nc < 4; nc++) {
      bf16x8 bv0 = *(const bf16x8*)&Vts[nc * 16 + fr][q * 8];
      bf16x8 bv1 = *(const bf16x8*)&Vts[nc * 16 + fr][32 + q * 8];
      oacc[nc] = __builtin_amdgcn_mfma_f32_16x16x32_bf16(ap0, bv0, oacc[nc], 0, 0, 0);
      oacc[nc] = __builtin_amdgcn_mfma_f32_16x16x32_bf16(ap1, bv1, oacc[nc], 0, 0, 0);
    }
  }
  // epilogue: g = O - Xs (bf16 normal + transposed), Dv partials
  float linv[4];
  #pragma unroll
  for (int r = 0; r < 4; r++) linv[r] = 1.0f / l[r];
  float dpart[4] = {};
  #pragma unroll
  for (int nc = 0; nc < 4; nc++) {
    ushort_t pg[4];
    #pragma unroll
    for (int r = 0; r < 4; r++) {
      int row = i0 + band + q * 4 + r;
      size_t gi = (size_t)(b * S_LEN + row) * E_DIM + h * HD + nc * 16 + fr;
      float o = oacc[nc][r] * linv[r];
      float g = o - Xs[gi];
      ushort_t bu = f2bu(g);
      Gb[gi] = bu;
      pg[r] = bu;
      dpart[r] += g * o;
    }
    int d = nc * 16 + fr;
    int s0 = i0 + band + q * 4;
    *(uint2*)(Gt + ((size_t)bh * HD + d) * S_LEN + s0) = *(uint2*)pg;
  }
  #pragma unroll
  for (int r = 0; r < 4; r++) {
    #pragma unroll
    for (int off = 1; off < 16; off <<= 1) dpart[r] += __shfl_xor(dpart[r], off, 64);
  }
  if (fr == 0) {
    #pragma unroll
    for (int r = 0; r < 4; r++) {
      size_t sid = (size_t)bh * S_LEN + i0 + band + q * 4 + r;
      mbuf[sid] = m[r] + log2f(l[r]);   // m' folds 1/l into the exponent
      Dv[sid] = dpart[r];
    }
  }
}

// ---- merged backward: block (bh, y): dq for i-tile y (y+1 units) then dk/dv for
//      j-tile y (16-y units) = 17 units/block. P = exp2(s*C2 - m'); SC folded into Qt/Kt.
//      Merged (not split): phases share staged tiles through L2 temporally — round-3
//      showed splitting costs 5.5x HBM fetch. ----
__global__ __launch_bounds__(256) void bwd_fused(const ushort_t* __restrict__ Qg,
                                                 const ushort_t* __restrict__ Kg,
                                                 const ushort_t* __restrict__ Vg,
                                                 const ushort_t* __restrict__ Gg,
                                                 const ushort_t* __restrict__ Qt,
                                                 const ushort_t* __restrict__ Kt,
                                                 const ushort_t* __restrict__ Gt,
                                                 const float* __restrict__ mbuf,
                                                 const float* __restrict__ Dv,
                                                 ushort_t* __restrict__ GQ,
                                                 ushort_t* __restrict__ GK,
                                                 ushort_t* __restrict__ GV) {
  int bh = blockIdx.x, y = blockIdx.y;
  int b = bh >> 4, h = bh & 15;
  int tid = threadIdx.x, lane = tid & 63, wv = tid >> 6;
  int fr = lane & 15, q = lane >> 4;
  int band = wv * 16;
  __shared__ ushort_t smem[6][64][72];

  // ================= phase A: dq for i-tile y =================
  {
    ushort_t (*Kts)[72] = smem[0];  // [j][d]
    ushort_t (*Vts)[72] = smem[1];  // [j][d]
    ushort_t (*Ktt)[72] = smem[2];  // [d][j] (pre-scaled by SC)
    ushort_t (*dSs)[72] = smem[3];
    int it = y, i0 = it * 64;

    const ushort_t* Qrow = Qg + (size_t)(b * S_LEN + i0 + band + fr) * E_DIM + h * HD;
    const ushort_t* Grow = Gg + (size_t)(b * S_LEN + i0 + band + fr) * E_DIM + h * HD;
    bf16x8 aq0 = ldg8(Qrow + q * 8), aq1 = ldg8(Qrow + 32 + q * 8);
    bf16x8 ag0 = ldg8(Grow + q * 8), ag1 = ldg8(Grow + 32 + q * 8);

    float mrow[4], Dr[4];
    #pragma unroll
    for (int r = 0; r < 4; r++) {
      size_t sid = (size_t)bh * S_LEN + i0 + band + q * 4 + r;
      mrow[r] = mbuf[sid]; Dr[r] = Dv[sid];
    }
    f32x4 dqacc[4] = {};

    #pragma unroll 1
    for (int jt = 0; jt <= it; jt++) {
      int j0 = jt * 64;
      __syncthreads();
      #pragma unroll
      for (int t = 0; t < 2; t++) {
        int u = tid + 256 * t;
        int r = u >> 3, c8 = (u & 7) * 8;
        *(uint4*)&Kts[r][c8] = *(const uint4*)(Kg + (size_t)(b * S_LEN + j0 + r) * E_DIM + h * HD + c8);
        *(uint4*)&Vts[r][c8] = *(const uint4*)(Vg + (size_t)(b * S_LEN + j0 + r) * E_DIM + h * HD + c8);
        *(uint4*)&Ktt[r][c8] = *(const uint4*)(Kt + (size_t)(bh * HD + r) * S_LEN + j0 + c8);
      }
      __syncthreads();
      f32x4 sA[4], dpA[4];
      #pragma unroll
      for (int nc = 0; nc < 4; nc++) {
        bf16x8 bk0 = *(const bf16x8*)&Kts[nc * 16 + fr][q * 8];
        bf16x8 bk1 = *(const bf16x8*)&Kts[nc * 16 + fr][32 + q * 8];
        bf16x8 bv0 = *(const bf16x8*)&Vts[nc * 16 + fr][q * 8];
        bf16x8 bv1 = *(const bf16x8*)&Vts[nc * 16 + fr][32 + q * 8];
        f32x4 z = {};
        z = __builtin_amdgcn_mfma_f32_16x16x32_bf16(aq0, bk0, z, 0, 0, 0);
        sA[nc] = __builtin_amdgcn_mfma_f32_16x16x32_bf16(aq1, bk1, z, 0, 0, 0);
        f32x4 z2 = {};
        z2 = __builtin_amdgcn_mfma_f32_16x16x32_bf16(ag0, bv0, z2, 0, 0, 0);
        dpA[nc] = __builtin_amdgcn_mfma_f32_16x16x32_bf16(ag1, bv1, z2, 0, 0, 0);
      }
      #pragma unroll
      for (int nc = 0; nc < 4; nc++)
        #pragma unroll
        for (int r = 0; r < 4; r++) {
          int row = i0 + band + q * 4 + r;
          int col = j0 + nc * 16 + fr;
          float ds = 0.f;
          if (col <= row) {
            float P = exp2f(fmaf(sA[nc][r], C2_C, -mrow[r]));
            ds = P * (dpA[nc][r] - Dr[r]);   // SC lives in Kt
          }
          dSs[band + q * 4 + r][nc * 16 + fr] = f2bu(ds);  // wave-private
        }
      bf16x8 ad0 = *(const bf16x8*)&dSs[band + fr][q * 8];
      bf16x8 ad1 = *(const bf16x8*)&dSs[band + fr][32 + q * 8];
      #pragma unroll
      for (int nc = 0; nc < 4; nc++) {
        bf16x8 bt0 = *(const bf16x8*)&Ktt[nc * 16 + fr][q * 8];
        bf16x8 bt1 = *(const bf16x8*)&Ktt[nc * 16 + fr][32 + q * 8];
        dqacc[nc] = __builtin_amdgcn_mfma_f32_16x16x32_bf16(ad0, bt0, dqacc[nc], 0, 0, 0);
        dqacc[nc] = __builtin_amdgcn_mfma_f32_16x16x32_bf16(ad1, bt1, dqacc[nc], 0, 0, 0);
      }
    }
    #pragma unroll
    for (int nc = 0; nc < 4; nc++)
      #pragma unroll
      for (int r = 0; r < 4; r++) {
        int row = i0 + band + q * 4 + r;
        size_t gi = (size_t)(b * S_LEN + row) * E_DIM + h * HD + nc * 16 + fr;
        GQ[gi] = f2bu(dqacc[nc][r]);
      }
  }

  // ================= phase B: dk/dv for j-tile y =================
  {
    ushort_t (*Qs_)[72] = smem[0];  // [i][d]
    ushort_t (*Gs_)[72] = smem[1];  // [i][d]
    ushort_t (*Qtt)[72] = smem[2];  // [d][i] (pre-scaled by SC)
    ushort_t (*Gtt)[72] = smem[3];  // [d][i]
    ushort_t (*PT)[72]  = smem[4];  // [j][i]
    ushort_t (*dST)[72] = smem[5];  // [j][i]
    int jt = y, j0 = jt * 64;

    const ushort_t* Krow = Kg + (size_t)(b * S_LEN + j0 + band + fr) * E_DIM + h * HD;
    const ushort_t* Vrow = Vg + (size_t)(b * S_LEN + j0 + band + fr) * E_DIM + h * HD;
    bf16x8 ak0 = ldg8(Krow + q * 8), ak1 = ldg8(Krow + 32 + q * 8);
    bf16x8 av0 = ldg8(Vrow + q * 8), av1 = ldg8(Vrow + 32 + q * 8);

    f32x4 dkacc[4] = {}, dvacc[4] = {};

    #pragma unroll 1
    for (int i_t = jt; i_t < 16; i_t++) {
      int i0 = i_t * 64;
      __syncthreads();
      #pragma unroll
      for (int t = 0; t < 2; t++) {
        int u = tid + 256 * t;
        int r = u >> 3, c8 = (u & 7) * 8;
        *(uint4*)&Qs_[r][c8] = *(const uint4*)(Qg + (size_t)(b * S_LEN + i0 + r) * E_DIM + h * HD + c8);
        *(uint4*)&Gs_[r][c8] = *(const uint4*)(Gg + (size_t)(b * S_LEN + i0 + r) * E_DIM + h * HD + c8);
        *(uint4*)&Qtt[r][c8] = *(const uint4*)(Qt + (size_t)(bh * HD + r) * S_LEN + i0 + c8);
        *(uint4*)&Gtt[r][c8] = *(const uint4*)(Gt + (size_t)(bh * HD + r) * S_LEN + i0 + c8);
      }
      __syncthreads();
      float mc[4], Dc[4];
      #pragma unroll
      for (int nc = 0; nc < 4; nc++) {
        size_t sid = (size_t)bh * S_LEN + i0 + nc * 16 + fr;
        mc[nc] = mbuf[sid]; Dc[nc] = Dv[sid];
      }
      f32x4 stA[4], dptA[4];
      #pragma unroll
      for (int nc = 0; nc < 4; nc++) {
        bf16x8 bq0 = *(const bf16x8*)&Qs_[nc * 16 + fr][q * 8];
        bf16x8 bq1 = *(const bf16x8*)&Qs_[nc * 16 + fr][32 + q * 8];
        bf16x8 bg0 = *(const bf16x8*)&Gs_[nc * 16 + fr][q * 8];
        bf16x8 bg1 = *(const bf16x8*)&Gs_[nc * 16 + fr][32 + q * 8];
        f32x4 z = {};
        z = __builtin_amdgcn_mfma_f32_16x16x32_bf16(ak0, bq0, z, 0, 0, 0);
        stA[nc] = __builtin_amdgcn_mfma_f32_16x16x32_bf16(ak1, bq1, z, 0, 0, 0);
        f32x4 z2 = {};
        z2 = __builtin_amdgcn_mfma_f32_16x16x32_bf16(av0, bg0, z2, 0, 0, 0);
        dptA[nc] = __builtin_amdgcn_mfma_f32_16x16x32_bf16(av1, bg1, z2, 0, 0, 0);
      }
      #pragma unroll
      for (int nc = 0; nc < 4; nc++)
        #pragma unroll
        for (int r = 0; r < 4; r++) {
          int jrow = j0 + band + q * 4 + r;
          int icol = i0 + nc * 16 + fr;
          float P = 0.f, ds = 0.f;
          if (icol >= jrow) {
            P = exp2f(fmaf(stA[nc][r], C2_C, -mc[nc]));
            ds = P * (dptA[nc][r] - Dc[nc]);   // SC lives in Qt
          }
          PT[band + q * 4 + r][nc * 16 + fr] = f2bu(P);   // wave-private
          dST[band + q * 4 + r][nc * 16 + fr] = f2bu(ds);
        }
      bf16x8 ap0 = *(const bf16x8*)&PT[band + fr][q * 8];
      bf16x8 ap1 = *(const bf16x8*)&PT[band + fr][32 + q * 8];
      bf16x8 ad0 = *(const bf16x8*)&dST[band + fr][q * 8];
      bf16x8 ad1 = *(const bf16x8*)&dST[band + fr][32 + q * 8];
      #pragma unroll
      for (int nc = 0; nc < 4; nc++) {
        bf16x8 bg0 = *(const bf16x8*)&Gtt[nc * 16 + fr][q * 8];
        bf16x8 bg1 = *(const bf16x8*)&Gtt[nc * 16 + fr][32 + q * 8];
        bf16x8 bq0 = *(const bf16x8*)&Qtt[nc * 16 + fr][q * 8];
        bf16x8 bq1 = *(const bf16x8*)&Qtt[nc * 16 + fr][32 + q * 8];
        dvacc[nc] = __builtin_amdgcn_mfma_f32_16x16x32_bf16(ap0, bg0, dvacc[nc], 0, 0, 0);
        dvacc[nc] = __builtin_amdgcn_mfma_f32_16x16x32_bf16(ap1, bg1, dvacc[nc], 0, 0, 0);
        dkacc[nc] = __builtin_amdgcn_mfma_f32_16x16x32_bf16(ad0, bq0, dkacc[nc], 0, 0, 0);
        dkacc[nc] = __builtin_amdgcn_mfma_f32_16x16x32_bf16(ad1, bq1, dkacc[nc], 0, 0, 0);
      }
    }
    #pragma unroll
    for (int nc = 0; nc < 4; nc++)
      #pragma unroll
      for (int r = 0; r < 4; r++) {
        int jrow = j0 + band + q * 4 + r;
        size_t gi = (size_t)(b * S_LEN + jrow) * E_DIM + h * HD + nc * 16 + fr;
        GK[gi] = f2bu(dkacc[nc][r]);
        GV[gi] = f2bu(dvacc[nc][r]);
      }
  }
}

// ---------------- launch ----------------
extern "C" void kernel_launch(void* const* d_in, const int* in_sizes, int n_in,
                              void* d_out, int out_size, void* d_ws, size_t ws_size,
                              hipStream_t stream) {
  const float* T1 = (const float*)d_in[0];
  const float* Wq = (const float*)d_in[1];
  const float* Wk = (const float*)d_in[2];
  const float* Wv = (const float*)d_in[3];
  const float* Wo = (const float*)d_in[4];

  const size_t M2 = 2097152;   // 2048*1024
  const size_t M1 = 1048576;
  float* w = (float*)d_ws;
  float* Xs = w;                       // 8 MB fp32 target
  float* mS = Xs + M2;                 // 64K f32 (stores m')
  float* DvS = mS + 65536;
  ushort_t* u = (ushort_t*)(DvS + 65536);
  ushort_t* W0 = u;          ushort_t* W1 = W0 + M1;  ushort_t* W2 = W1 + M1;
  ushort_t* W3 = W2 + M1;    ushort_t* W4 = W3 + M1;  ushort_t* W5 = W4 + M1;
  ushort_t* Qb = W5 + M1;    ushort_t* Kb = Qb + M2;  ushort_t* Vb = Kb + M2;
  ushort_t* Qt = Vb + M2;    ushort_t* Kt = Qt + M2;  ushort_t* Vt = Kt + M2;
  ushort_t* Gt = Vt + M2;
  ushort_t* Gb = Gt + M2;
  ushort_t* GQb = Gb + M2;   ushort_t* GKb = GQb + M2; ushort_t* GVb = GKb + M2;
  ushort_t* X2b = GVb + M2;
  float* X2 = (float*)d_out;

  // stage-1 aliases (all overwritten before stage-2 uses the slots)
  float* Mf  = (float*)Qb;       // 4 MB
  float* M2f = (float*)Kb;       // 4 MB
  ushort_t* Mb  = Gt;            // 2 MB
  ushort_t* Nb  = Vb;            // 2 MB
  ushort_t* AtB = Qt;            // 2 MB
  ushort_t* T1b = Kt;            // 4 MB

  // iter-1 shortcut aliases (dead before their regions' stage-2 consumers)
  float* Sf  = (float*)GQb;      // 8 MB fp32 scan partials (spans GQb+GKb)
  float* tot = mS;               // 128 KB chunk totals (mS rewritten by fwd of iter 2)
  ushort_t* Sb = GVb;            // 4 MB bf16 scan result

  dim3 pgrid(16, 16);
  dim3 sgrid(16, 16);       // 1024x1024 GEMMs
  dim3 ggrid(16, 32);       // 2048x1024 GEMMs
  dim3 ggrid3(16, 32, 3);   // QKV
  dim3 agrid(BH_CNT, 16);   // attention

  // ---- stage 1 (algebraic): Xs = T * Wo * (3LR·I - 3LR²·M + LR³·M²),  M = WoᵀWo ----
  k_cast<<<(M2 / 4 + 255) / 256, 256, 0, stream>>>(T1, T1b, (int)(M2 / 4));
  prep_w<<<pgrid, 256, 0, stream>>>(Wo, W0, W1);
  // M = W1·W1ᵀ  (fp32 + bf16)
  gemm_mf<4, 1><<<sgrid, 256, 0, stream>>>(W1, nullptr, nullptr, W1, nullptr, nullptr,
                                           Mf, Mb, nullptr, nullptr,
                                           nullptr, nullptr, nullptr, 0.f);
  // M2 = Mb·Mbᵀ (M symmetric)
  gemm_mf<3, 1><<<sgrid, 256, 0, stream>>>(Mb, nullptr, nullptr, Mb, nullptr, nullptr,
                                           M2f, nullptr, nullptr, nullptr,
                                           nullptr, nullptr, nullptr, 0.f);
  k_formN<<<(M1 + 255) / 256, 256, 0, stream>>>(Mf, M2f, Nb);
  // AtB = N·Woᵀ  (symmetric N; this is (Wo·N)ᵀ in [N,K] form)
  gemm_mf<5, 1><<<sgrid, 256, 0, stream>>>(Nb, nullptr, nullptr, W0, nullptr, nullptr,
                                           nullptr, AtB, nullptr, nullptr,
                                           nullptr, nullptr, nullptr, 0.f);
  // stage-2 weights (W0/W1 free after AtB)
  prep_w<<<pgrid, 256, 0, stream>>>(Wq, W0, W3);
  prep_w<<<pgrid, 256, 0, stream>>>(Wk, W1, W4);
  prep_w<<<pgrid, 256, 0, stream>>>(Wv, W2, W5);
  // Xs = T1b·AtBᵀ (fp32)
  gemm_mf<3, 1><<<ggrid, 256, 0, stream>>>(T1b, nullptr, nullptr, AtB, nullptr, nullptr,
                                           Xs, nullptr, nullptr, nullptr,
                                           nullptr, nullptr, nullptr, 0.f);

  // ---- stage 2, iteration 1 (closed form): x=0 => Q=K=V=0, P exactly causal-uniform,
  //      dQ=dK=0, dV = P0^T(-Xs); x1 = LR * (P0^T Xs) * Wv via fp32 suffix scan + one GEMM ----
  k_scan1<<<dim3(E_DIM / 256, 2, 16), 256, 0, stream>>>(Xs, Sf, tot);
  k_scan2<<<dim3(E_DIM / 256, 2, 16), 256, 0, stream>>>(Sf, tot, Sb);
  gemm_mf<6, 1><<<ggrid, 256, 0, stream>>>(Sb, nullptr, nullptr, W5, nullptr, nullptr,
                                           X2, X2b, nullptr, nullptr,
                                           nullptr, nullptr, nullptr, LR_C);

  // ---- stage 2, iterations 2..3 (full PC gradient) ----
  for (int t = 1; t < 3; t++) {
    gemm_mf<0, 1><<<ggrid3, 256, 0, stream>>>(X2b, nullptr, nullptr, W0, W1, W2,
                                              nullptr, Qb, Kb, Vb,
                                              Qt, Kt, Vt, 0.f);
    fwd_fused<<<agrid, 256, 0, stream>>>(Qb, Kb, Vt, Xs, mS, Gb, Gt, DvS);
    bwd_fused<<<agrid, 256, 0, stream>>>(Qb, Kb, Vb, Gb, Qt, Kt, Gt, mS, DvS,
                                         GQb, GKb, GVb);
    gemm_mf<2, 3><<<ggrid, 256, 0, stream>>>(GQb, GKb, GVb, W3, W4, W5,
                                             X2, X2b, nullptr, nullptr,
                                             nullptr, nullptr, nullptr, -LR_C);
  }
}